// Round 1
// 1179.809 us; speedup vs baseline: 1.0075x; 1.0075x over previous
//
#include <hip/hip_runtime.h>
#include <cstdint>
#include <cstddef>

// LSTMClassifier R7: flag + tagless-bulk exchange replacing per-packet tagged LL polls.
// R6 diagnosis: per-packet self-validating polls re-fetch 32 KB per attempt per WG with
// agent-scope (cache-bypassing) loads; at 22k cy/step steady state that is O(10 TB/s)
// of attempted L3/fabric traffic (FETCH_SIZE 690 MB at HBM alone) -> congestion inflates
// every RTT -> more failed polls. Self-reinforcing equilibrium ~6x above latency model.
// R7 protocol: producers store tagless bf16x4 payload (relaxed agent 8B atomics),
// s_waitcnt vmcnt(0) per wave (payload at coherence point), then ONE u32 flag per
// producer wave. Consumers spin on 4-24 flag dwords only, then bulk-load payload once.
// Payload halves (no tags), spin traffic ~vanishes, one barrier per step removed.
// Flag-slot reuse safe under existing ring back-pressure; flags zeroed each launch.

constexpr int kN = 36, kH = 256, kG = 1024, kB = 32, kT = 128, kSpec = 6, kOut = 30;
constexpr int kHP = 264;   // LDS h stride (ushort)
constexpr int kD1 = 16;    // h1 ring depth (steps)

typedef __bf16 bf16;
typedef __bf16 bf16x8 __attribute__((ext_vector_type(8)));
typedef float f32x4 __attribute__((ext_vector_type(4)));
typedef unsigned long long u64;
typedef unsigned int u32;

__device__ __forceinline__ float sigm(float v) { return 1.f / (1.f + __expf(-v)); }
__device__ __forceinline__ float tanh_f(float v) {
  v = fminf(15.f, fmaxf(-15.f, v));
  float e = __expf(2.f * v);
  return (e - 1.f) / (e + 1.f);
}
__device__ __forceinline__ unsigned short f2bf(float f) {
  bf16 b = (bf16)f;
  return __builtin_bit_cast(unsigned short, b);
}
__device__ __forceinline__ u64 pload(const u64* p) {
  return __hip_atomic_load(p, __ATOMIC_RELAXED, __HIP_MEMORY_SCOPE_AGENT);
}
__device__ __forceinline__ void pstore(u64* p, u64 v) {
  __hip_atomic_store(p, v, __ATOMIC_RELAXED, __HIP_MEMORY_SCOPE_AGENT);
}
__device__ __forceinline__ u32 pload32(const u32* p) {
  return __hip_atomic_load(p, __ATOMIC_RELAXED, __HIP_MEMORY_SCOPE_AGENT);
}
__device__ __forceinline__ void pstore32(u32* p, u32 v) {
  __hip_atomic_store(p, v, __ATOMIC_RELAXED, __HIP_MEMORY_SCOPE_AGENT);
}
// acquire: orders the subsequent bulk payload loads after flag observation.
__device__ __forceinline__ void wait_flag(const u32* f, u32 want) {
  while (__hip_atomic_load(f, __ATOMIC_ACQUIRE, __HIP_MEMORY_SCOPE_AGENT) != want)
    __builtin_amdgcn_s_sleep(1);
}
__device__ __forceinline__ u64 pack4(float a, float b, float c, float d) {
  return (u64)f2bf(a) | ((u64)f2bf(b) << 16) | ((u64)f2bf(c) << 32) |
         ((u64)f2bf(d) << 48);
}

// ---- convert + permute weights fp32 -> bf16 MFMA B-fragment order ----
// packed[n][nt][ks][lane]: gate col g = nt*16 + (lane&15), k = ks*32 + (lane>>4)*8 + r.
__global__ __launch_bounds__(256) void k_convert(
    const float* __restrict__ wa, const float* __restrict__ wb, const float* __restrict__ wc,
    bf16* __restrict__ oa, bf16* __restrict__ ob, bf16* __restrict__ oc)
{
  const size_t total = (size_t)kN * 64 * 8 * 64;
  size_t gid = (size_t)blockIdx.x * 256 + threadIdx.x;
  if (gid >= total) return;
  const int lane = (int)(gid & 63);
  const int ks = (int)((gid >> 6) & 7);
  const int nt = (int)((gid >> 9) & 63);
  const int n = (int)(gid >> 15);
  const int g = nt * 16 + (lane & 15);
  const int k = ks * 32 + (lane >> 4) * 8;
  const size_t so = ((size_t)n * kG + g) * kH + k;

  const float4 a0 = *(const float4*)(wa + so), a1 = *(const float4*)(wa + so + 4);
  const float4 b0 = *(const float4*)(wb + so), b1 = *(const float4*)(wb + so + 4);
  const float4 c0 = *(const float4*)(wc + so), c1 = *(const float4*)(wc + so + 4);
  bf16x8 va, vb, vc;
  va[0]=(bf16)a0.x; va[1]=(bf16)a0.y; va[2]=(bf16)a0.z; va[3]=(bf16)a0.w;
  va[4]=(bf16)a1.x; va[5]=(bf16)a1.y; va[6]=(bf16)a1.z; va[7]=(bf16)a1.w;
  vb[0]=(bf16)b0.x; vb[1]=(bf16)b0.y; vb[2]=(bf16)b0.z; vb[3]=(bf16)b0.w;
  vb[4]=(bf16)b1.x; vb[5]=(bf16)b1.y; vb[6]=(bf16)b1.z; vb[7]=(bf16)b1.w;
  vc[0]=(bf16)c0.x; vc[1]=(bf16)c0.y; vc[2]=(bf16)c0.z; vc[3]=(bf16)c0.w;
  vc[4]=(bf16)c1.x; vc[5]=(bf16)c1.y; vc[6]=(bf16)c1.z; vc[7]=(bf16)c1.w;
  ((bf16x8*)oa)[gid] = va;
  ((bf16x8*)ob)[gid] = vb;
  ((bf16x8*)oc)[gid] = vc;
}

// ---- two concurrent recurrent chains ----
// Payload layout per h-matrix: u64[c=0..255][mc=0..7], u64 = bf16 rows (mc*4..mc*4+3)
// of column c. Publisher-register-natural (rows vary with acc reg index r).
// Flag lines: 16 u32 (64 B) per (stream, slot); entry = producerWG*4 + wave.
__global__ __launch_bounds__(256) __attribute__((amdgpu_waves_per_eu(1, 1)))
void k_lstm(
    const float* __restrict__ x, const float* __restrict__ Wih1,
    const float* __restrict__ bih1, const float* __restrict__ bhh1,
    const float* __restrict__ bih2, const float* __restrict__ bhh2,
    const bf16* __restrict__ pk1, const bf16* __restrict__ pk2i,
    const bf16* __restrict__ pk2h, float* __restrict__ h2_final,
    u64* __restrict__ pay1, u64* __restrict__ pay2,
    u32* __restrict__ flags1, u32* __restrict__ flags2, u32* __restrict__ prog)
{
  const int blk = blockIdx.x;
  const int tid = threadIdx.x, wv = tid >> 6, lane = tid & 63;
  const int l15 = lane & 15, l4 = lane >> 4;

  __shared__ alignas(16) unsigned short hs1[kB][kHP];

  if (blk < 72) {
    // ================= L1: h1 chain; WG j owns h1-cols [j*128,(j+1)*128) =========
    const int n = blk >> 1, j = blk & 1;
    __shared__ float xsh[kT][kB];
    for (int i = tid; i < kB * kT; i += 256) {
      int b = i >> 7, t = i & 127;
      xsh[t][b] = x[((size_t)b * kT + t) * kN + n];
    }
    bf16x8 W[2][4][8]; // 256 VGPRs
    {
      const bf16x8* base = (const bf16x8*)pk1 + (size_t)n * 32768;
#pragma unroll
      for (int jj = 0; jj < 2; ++jj)
#pragma unroll
        for (int gt = 0; gt < 4; ++gt)
#pragma unroll
          for (int ks = 0; ks < 8; ++ks)
            W[jj][gt][ks] = base[(size_t)(gt * 16 + j * 8 + wv * 2 + jj) * 512 + ks * 64 + lane];
    }
    float wih[2][4], bg[2][4];
#pragma unroll
    for (int jj = 0; jj < 2; ++jj)
#pragma unroll
      for (int gt = 0; gt < 4; ++gt) {
        int g = gt * 256 + j * 128 + wv * 32 + jj * 16 + l15;
        wih[jj][gt] = Wih1[n * kG + g];
        bg[jj][gt] = bih1[n * kG + g] + bhh1[n * kG + g];
      }
    float cst[2][2][4];
#pragma unroll
    for (int a = 0; a < 2; ++a)
#pragma unroll
      for (int b = 0; b < 2; ++b)
#pragma unroll
        for (int r = 0; r < 4; ++r) cst[a][b][r] = 0.f;

    u64* payn = pay1 + (size_t)n * kD1 * 2048;
    u32* fl1 = flags1 + (size_t)n * kD1 * 16;
    u32* pg = prog + n * 4;
    const int pc0 = (1 - j) * 128, myb = j * 128 + wv * 32;
    __syncthreads();

#pragma unroll 1
    for (int t = 0; t < kT; ++t) {
      if ((t & 7) == 0 && t) { // ring back-pressure vs slowest L2 quarter
        if (tid == 0) {
          for (;;) {
            u32 m0 = pload32(&pg[0]), m1 = pload32(&pg[1]);
            u32 m2 = pload32(&pg[2]), m3 = pload32(&pg[3]);
            u32 mn = m0 < m1 ? m0 : m1;
            mn = mn < m2 ? mn : m2;
            mn = mn < m3 ? mn : m3;
            if ((int)mn + 8 >= t) break;
            __builtin_amdgcn_s_sleep(2);
          }
        }
        __syncthreads();
      }
      f32x4 acc[2][2][4];
#pragma unroll
      for (int mt = 0; mt < 2; ++mt)
#pragma unroll
        for (int jj = 0; jj < 2; ++jj)
#pragma unroll
          for (int gt = 0; gt < 4; ++gt)
#pragma unroll
            for (int r = 0; r < 4; ++r)
              acc[mt][jj][gt][r] = xsh[t][mt * 16 + l4 * 4 + r] * wih[jj][gt] + bg[jj][gt];
      if (t > 0) {
        const int sl = (t - 1) % kD1;
        // sibling published h1(t-1) with flag value t (4 wave-flags)
        if (wv == 0 && lane < 4) wait_flag(fl1 + sl * 16 + (1 - j) * 4 + lane, (u32)t);
        __syncthreads();   // also protects hs1 own-half writes (t-1) vs reads (t)
        {
          const u64* ps = payn + (size_t)sl * 2048;
          const int c = pc0 + (tid >> 1), mb = (tid & 1) * 16;
          u64 v[4];
#pragma unroll
          for (int i = 0; i < 4; ++i)
            v[i] = pload(ps + (size_t)c * 8 + (tid & 1) * 4 + i);
#pragma unroll
          for (int i = 0; i < 4; ++i) {
            hs1[mb + 4 * i + 0][c] = (unsigned short)v[i];
            hs1[mb + 4 * i + 1][c] = (unsigned short)(v[i] >> 16);
            hs1[mb + 4 * i + 2][c] = (unsigned short)(v[i] >> 32);
            hs1[mb + 4 * i + 3][c] = (unsigned short)(v[i] >> 48);
          }
        }
        __syncthreads();
#pragma unroll
        for (int ks = 0; ks < 8; ++ks) {
          bf16x8 A0 = *(const bf16x8*)&hs1[l15][ks * 32 + l4 * 8];
          bf16x8 A1 = *(const bf16x8*)&hs1[16 + l15][ks * 32 + l4 * 8];
#pragma unroll
          for (int jj = 0; jj < 2; ++jj)
#pragma unroll
            for (int gt = 0; gt < 4; ++gt) {
              acc[0][jj][gt] = __builtin_amdgcn_mfma_f32_16x16x32_bf16(A0, W[jj][gt][ks], acc[0][jj][gt], 0, 0, 0);
              acc[1][jj][gt] = __builtin_amdgcn_mfma_f32_16x16x32_bf16(A1, W[jj][gt][ks], acc[1][jj][gt], 0, 0, 0);
            }
        }
      }
      float hv[2][2][4];
#pragma unroll
      for (int mt = 0; mt < 2; ++mt)
#pragma unroll
        for (int jj = 0; jj < 2; ++jj)
#pragma unroll
          for (int r = 0; r < 4; ++r) {
            float cc = sigm(acc[mt][jj][1][r]) * cst[mt][jj][r]
                     + sigm(acc[mt][jj][0][r]) * tanh_f(acc[mt][jj][2][r]);
            cst[mt][jj][r] = cc;
            hv[mt][jj][r] = sigm(acc[mt][jj][3][r]) * tanh_f(cc);
          }
      // publish h1(t): tagless bf16x4 payload
      u64* pub = payn + (size_t)(t % kD1) * 2048;
#pragma unroll
      for (int jj = 0; jj < 2; ++jj)
#pragma unroll
        for (int mt = 0; mt < 2; ++mt) {
          int c = myb + jj * 16 + l15;
          pstore(&pub[(size_t)c * 8 + mt * 4 + l4],
                 pack4(hv[mt][jj][0], hv[mt][jj][1], hv[mt][jj][2], hv[mt][jj][3]));
        }
      // local half straight into LDS for next step (overlaps store drain)
#pragma unroll
      for (int mt = 0; mt < 2; ++mt)
#pragma unroll
        for (int jj = 0; jj < 2; ++jj)
#pragma unroll
          for (int r = 0; r < 4; ++r)
            hs1[mt * 16 + l4 * 4 + r][myb + jj * 16 + l15] = f2bf(hv[mt][jj][r]);
      asm volatile("s_waitcnt vmcnt(0)" ::: "memory"); // payload at coherence point
      if (lane == 0) pstore32(fl1 + (t % kD1) * 16 + j * 4 + wv, (u32)(t + 1));
      // no loop-end barrier: next iteration's post-flag barrier protects hs1
    }
  } else {
    // ====== L2: h2 chain; WG q owns h2-cols [q*64,(q+1)*64); u in-register =======
    const int bb = blk - 72, n = bb >> 2, q = bb & 3;
    __shared__ alignas(16) unsigned short hs2[kB][kHP];

    bf16x8 Wi[4][8], Wh[4][8]; // 128 + 128 VGPRs
    {
      const bf16x8* bi = (const bf16x8*)pk2i + (size_t)n * 32768;
      const bf16x8* bh = (const bf16x8*)pk2h + (size_t)n * 32768;
#pragma unroll
      for (int gt = 0; gt < 4; ++gt)
#pragma unroll
        for (int ks = 0; ks < 8; ++ks) {
          size_t o = (size_t)(gt * 16 + q * 4 + wv) * 512 + ks * 64 + lane;
          Wi[gt][ks] = bi[o];
          Wh[gt][ks] = bh[o];
        }
    }
    const int col = q * 64 + wv * 16 + l15;
    float bg[4];
#pragma unroll
    for (int gt = 0; gt < 4; ++gt) {
      int g = gt * 256 + col;
      bg[gt] = bih2[n * kG + g] + bhh2[n * kG + g];
    }
    float cst[2][4];
#pragma unroll
    for (int mt = 0; mt < 2; ++mt)
#pragma unroll
      for (int r = 0; r < 4; ++r) cst[mt][r] = 0.f;

    u64* payn = pay1 + (size_t)n * kD1 * 2048;
    u64* p2n = pay2 + (size_t)n * 2 * 2048;
    u32* fl1 = flags1 + (size_t)n * kD1 * 16;
    u32* fl2 = flags2 + (size_t)n * 2 * 16;
    u32* pg = prog + n * 4 + q;
    __syncthreads();

#pragma unroll 1
    for (int t = 0; t < kT; ++t) {
      // (a) wait h1(t) [8 wave-flags] and h2(t-1) [16 wave-flags] concurrently
      if (wv == 0) {
        if (lane < 8) wait_flag(fl1 + (t % kD1) * 16 + lane, (u32)(t + 1));
        else if (t > 0 && lane < 24) wait_flag(fl2 + ((t - 1) & 1) * 16 + (lane - 8), (u32)t);
      }
      __syncthreads();
      // (b) bulk-load both payloads once, stage into hs1/hs2 (column c = tid)
      u64 v1[8], v2[8];
      const u64* ph1 = payn + (size_t)(t % kD1) * 2048;
#pragma unroll
      for (int i = 0; i < 8; ++i) v1[i] = pload(ph1 + (size_t)tid * 8 + i);
      if (t > 0) {
        const u64* ph2 = p2n + (size_t)((t - 1) & 1) * 2048;
#pragma unroll
        for (int i = 0; i < 8; ++i) v2[i] = pload(ph2 + (size_t)tid * 8 + i);
      }
#pragma unroll
      for (int i = 0; i < 8; ++i) {
        hs1[4 * i + 0][tid] = (unsigned short)v1[i];
        hs1[4 * i + 1][tid] = (unsigned short)(v1[i] >> 16);
        hs1[4 * i + 2][tid] = (unsigned short)(v1[i] >> 32);
        hs1[4 * i + 3][tid] = (unsigned short)(v1[i] >> 48);
      }
      if (t > 0) {
#pragma unroll
        for (int i = 0; i < 8; ++i) {
          hs2[4 * i + 0][tid] = (unsigned short)v2[i];
          hs2[4 * i + 1][tid] = (unsigned short)(v2[i] >> 16);
          hs2[4 * i + 2][tid] = (unsigned short)(v2[i] >> 32);
          hs2[4 * i + 3][tid] = (unsigned short)(v2[i] >> 48);
        }
      }
      __syncthreads();
      if (tid == 0) pstore32(pg, (u32)(t + 1)); // h1(t) staged; ring slot reusable
      // (c) u = Wih2 * h1(t) + bg2, then Whh2 * h2(t-1)
      f32x4 acc[2][4];
#pragma unroll
      for (int mt = 0; mt < 2; ++mt)
#pragma unroll
        for (int gt = 0; gt < 4; ++gt)
#pragma unroll
          for (int r = 0; r < 4; ++r) acc[mt][gt][r] = bg[gt];
#pragma unroll
      for (int ks = 0; ks < 8; ++ks) {
        bf16x8 A0 = *(const bf16x8*)&hs1[l15][ks * 32 + l4 * 8];
        bf16x8 A1 = *(const bf16x8*)&hs1[16 + l15][ks * 32 + l4 * 8];
#pragma unroll
        for (int gt = 0; gt < 4; ++gt) {
          acc[0][gt] = __builtin_amdgcn_mfma_f32_16x16x32_bf16(A0, Wi[gt][ks], acc[0][gt], 0, 0, 0);
          acc[1][gt] = __builtin_amdgcn_mfma_f32_16x16x32_bf16(A1, Wi[gt][ks], acc[1][gt], 0, 0, 0);
        }
      }
      if (t > 0) {
#pragma unroll
        for (int ks = 0; ks < 8; ++ks) {
          bf16x8 A0 = *(const bf16x8*)&hs2[l15][ks * 32 + l4 * 8];
          bf16x8 A1 = *(const bf16x8*)&hs2[16 + l15][ks * 32 + l4 * 8];
#pragma unroll
          for (int gt = 0; gt < 4; ++gt) {
            acc[0][gt] = __builtin_amdgcn_mfma_f32_16x16x32_bf16(A0, Wh[gt][ks], acc[0][gt], 0, 0, 0);
            acc[1][gt] = __builtin_amdgcn_mfma_f32_16x16x32_bf16(A1, Wh[gt][ks], acc[1][gt], 0, 0, 0);
          }
        }
      }
      // (d) cell + publish h2(t)
      float hv[2][4];
#pragma unroll
      for (int mt = 0; mt < 2; ++mt)
#pragma unroll
        for (int r = 0; r < 4; ++r) {
          float cc = sigm(acc[mt][1][r]) * cst[mt][r]
                   + sigm(acc[mt][0][r]) * tanh_f(acc[mt][2][r]);
          cst[mt][r] = cc;
          hv[mt][r] = sigm(acc[mt][3][r]) * tanh_f(cc);
        }
      u64* pub = p2n + (size_t)(t & 1) * 2048;
#pragma unroll
      for (int mt = 0; mt < 2; ++mt)
        pstore(&pub[(size_t)col * 8 + mt * 4 + l4],
               pack4(hv[mt][0], hv[mt][1], hv[mt][2], hv[mt][3]));
      if (t == kT - 1) {
#pragma unroll
        for (int mt = 0; mt < 2; ++mt)
#pragma unroll
          for (int r = 0; r < 4; ++r)
            h2_final[((size_t)n * kB + (mt * 16 + l4 * 4 + r)) * kH + col] = hv[mt][r];
      }
      asm volatile("s_waitcnt vmcnt(0)" ::: "memory"); // payload at coherence point
      if (lane == 0) pstore32(fl2 + (t & 1) * 16 + q * 4 + wv, (u32)(t + 1));
      // no loop-end barrier: next iteration's post-flag barrier protects hs1/hs2
    }
  }
}

// ---- head ----
__global__ __launch_bounds__(256) void k_head1(
    const float* __restrict__ spec, const float* __restrict__ Wspec,
    const float* __restrict__ bspec, const float* __restrict__ Wp1,
    const float* __restrict__ h2f, float* __restrict__ partial)
{
  const int kc = blockIdx.x;
  const int b = blockIdx.y;
  const int o = threadIdx.x;
  __shared__ float fs[kH];
  if (kc < kN) {
    fs[o] = h2f[((size_t)kc * kB + b) * kH + o];
  } else {
    float v = bspec[o];
#pragma unroll
    for (int s = 0; s < kSpec; ++s) v += spec[b * kSpec + s] * Wspec[s * kH + o];
    fs[o] = v;
  }
  __syncthreads();
  const float* __restrict__ wp = Wp1 + (size_t)kc * 256 * kH + o;
  float a = 0.f;
#pragma unroll 8
  for (int i = 0; i < 256; ++i) a += fs[i] * wp[(size_t)i * kH];
  partial[((size_t)kc * kB + b) * kH + o] = a;
}

__global__ __launch_bounds__(256) void k_head2(
    const float* __restrict__ bp1, const float* __restrict__ Wp2,
    const float* __restrict__ bp2, const float* __restrict__ partial,
    float* __restrict__ out)
{
  const int b = blockIdx.x;
  const int o = threadIdx.x;
  __shared__ float hid[kH];
  float a = bp1[o];
#pragma unroll
  for (int kc = 0; kc < kN + 1; ++kc) a += partial[((size_t)kc * kB + b) * kH + o];
  hid[o] = fmaxf(a, 0.f);
  __syncthreads();
  if (o < kOut) {
    float r = bp2[o];
#pragma unroll 8
    for (int h = 0; h < kH; ++h) r += hid[h] * Wp2[h * kOut + o];
    out[b * kOut + o] = r;
  }
}

extern "C" void kernel_launch(void* const* d_in, const int* in_sizes, int n_in,
                              void* d_out, int out_size, void* d_ws, size_t ws_size,
                              hipStream_t stream) {
  const float* x = (const float*)d_in[0];
  const float* spec = (const float*)d_in[1];
  const float* Wih1 = (const float*)d_in[2];
  const float* Whh1 = (const float*)d_in[3];
  const float* bih1 = (const float*)d_in[4];
  const float* bhh1 = (const float*)d_in[5];
  const float* Wih2 = (const float*)d_in[6];
  const float* Whh2 = (const float*)d_in[7];
  const float* bih2 = (const float*)d_in[8];
  const float* bhh2 = (const float*)d_in[9];
  const float* Wspec = (const float*)d_in[10];
  const float* bspec = (const float*)d_in[11];
  const float* Wp1 = (const float*)d_in[12];
  const float* bp1 = (const float*)d_in[13];
  const float* Wp2 = (const float*)d_in[14];
  const float* bp2 = (const float*)d_in[15];
  float* out = (float*)d_out;

  // ws (~70 MB): [prog 4K][flags1 36K][flags2 4.5K][pay1 9.4M][pay2 1.2M]
  //              [pk1|pk2i|pk2h 56.6M][h2_final 4.7M... actually 1.2M][partial 1.2M]
  // prog + all flags zeroed each launch (0 never matches wanted tags 1..128).
  const size_t WSZ = (size_t)kN * kG * kH;
  u32* prog = (u32*)d_ws;
  u32* flags1 = (u32*)((char*)d_ws + 4096);                 // 36*16*16 u32 = 36,864 B
  u32* flags2 = flags1 + (size_t)kN * kD1 * 16;             // 36*2*16 u32 = 4,608 B
  u64* pay1 = (u64*)((char*)d_ws + 45568);                  // 36*16*2048 u64 = 9.44 MB
  u64* pay2 = pay1 + (size_t)kN * kD1 * 2048;               // 36*2*2048 u64 = 1.18 MB
  bf16* pk1 = (bf16*)(pay2 + (size_t)kN * 2 * 2048);
  bf16* pk2i = pk1 + WSZ;
  bf16* pk2h = pk2i + WSZ;
  float* h2_final = (float*)(pk2h + WSZ);
  float* partial = h2_final + (size_t)kN * kB * kH;

  hipMemsetAsync(d_ws, 0, 45568, stream); // prog + flag lines

  const size_t groups = (size_t)kN * 64 * 8 * 64;
  k_convert<<<dim3((unsigned)((groups + 255) / 256)), dim3(256), 0, stream>>>(
      Whh1, Wih2, Whh2, pk1, pk2i, pk2h);
  k_lstm<<<dim3(216), dim3(256), 0, stream>>>(
      x, Wih1, bih1, bhh1, bih2, bhh2, pk1, pk2i, pk2h, h2_final,
      pay1, pay2, flags1, flags2, prog);
  k_head1<<<dim3(kN + 1, kB), dim3(256), 0, stream>>>(spec, Wspec, bspec, Wp1, h2_final, partial);
  k_head2<<<dim3(kB), dim3(256), 0, stream>>>(bp1, Wp2, bp2, partial, out);
}

// Round 2
// 895.977 us; speedup vs baseline: 1.3266x; 1.3168x over previous
//
#include <hip/hip_runtime.h>
#include <cstdint>
#include <cstddef>

// LSTMClassifier R8: hot spins (no s_sleep, relaxed polls) to defeat DVFS downclock.
// R7 post-mortem: FETCH halved, conflicts -70%, dur UNCHANGED. MfmaUtil (8%) and
// VALUBusy (20.5%) independently imply ~8000 cycles/step, but wall time is 9.2us/step
// -> effective clock ~870 MHz (~1/3 of 2.4 GHz). The kernel's profile (10% occupancy,
// waves_per_eu(1,1), s_sleep in every wait loop) tells the DVFS governor to downclock.
// R8: identical protocol to R7, but all waits are hot relaxed spins:
//  - no s_sleep anywhere (sleep is the strongest downclock hint),
//  - flag polls use RELAXED loads (no per-iteration vmcnt(0)+buffer_inv from acquire;
//    ordering is safe: payload loads are cache-bypassing agent atomics issued after the
//    post-flag __syncthreads, and producers drain vmcnt(0) before flag-store).
// Spin cost per iteration is naturally ~600cy (load + waitcnt), and R6 proved poll
// traffic volume does not move duration.

constexpr int kN = 36, kH = 256, kG = 1024, kB = 32, kT = 128, kSpec = 6, kOut = 30;
constexpr int kHP = 264;   // LDS h stride (ushort)
constexpr int kD1 = 16;    // h1 ring depth (steps)

typedef __bf16 bf16;
typedef __bf16 bf16x8 __attribute__((ext_vector_type(8)));
typedef float f32x4 __attribute__((ext_vector_type(4)));
typedef unsigned long long u64;
typedef unsigned int u32;

__device__ __forceinline__ float sigm(float v) { return 1.f / (1.f + __expf(-v)); }
__device__ __forceinline__ float tanh_f(float v) {
  v = fminf(15.f, fmaxf(-15.f, v));
  float e = __expf(2.f * v);
  return (e - 1.f) / (e + 1.f);
}
__device__ __forceinline__ unsigned short f2bf(float f) {
  bf16 b = (bf16)f;
  return __builtin_bit_cast(unsigned short, b);
}
__device__ __forceinline__ u64 pload(const u64* p) {
  return __hip_atomic_load(p, __ATOMIC_RELAXED, __HIP_MEMORY_SCOPE_AGENT);
}
__device__ __forceinline__ void pstore(u64* p, u64 v) {
  __hip_atomic_store(p, v, __ATOMIC_RELAXED, __HIP_MEMORY_SCOPE_AGENT);
}
__device__ __forceinline__ u32 pload32(const u32* p) {
  return __hip_atomic_load(p, __ATOMIC_RELAXED, __HIP_MEMORY_SCOPE_AGENT);
}
__device__ __forceinline__ void pstore32(u32* p, u32 v) {
  __hip_atomic_store(p, v, __ATOMIC_RELAXED, __HIP_MEMORY_SCOPE_AGENT);
}
// Hot relaxed spin. Ordering: payload loads are agent-scope (cache-bypassing) atomics
// issued after the post-flag __syncthreads; producer drained vmcnt(0) before flag.
__device__ __forceinline__ void wait_flag(const u32* f, u32 want) {
  while (pload32(f) != want) { }
}
__device__ __forceinline__ u64 pack4(float a, float b, float c, float d) {
  return (u64)f2bf(a) | ((u64)f2bf(b) << 16) | ((u64)f2bf(c) << 32) |
         ((u64)f2bf(d) << 48);
}

// ---- convert + permute weights fp32 -> bf16 MFMA B-fragment order ----
// packed[n][nt][ks][lane]: gate col g = nt*16 + (lane&15), k = ks*32 + (lane>>4)*8 + r.
__global__ __launch_bounds__(256) void k_convert(
    const float* __restrict__ wa, const float* __restrict__ wb, const float* __restrict__ wc,
    bf16* __restrict__ oa, bf16* __restrict__ ob, bf16* __restrict__ oc)
{
  const size_t total = (size_t)kN * 64 * 8 * 64;
  size_t gid = (size_t)blockIdx.x * 256 + threadIdx.x;
  if (gid >= total) return;
  const int lane = (int)(gid & 63);
  const int ks = (int)((gid >> 6) & 7);
  const int nt = (int)((gid >> 9) & 63);
  const int n = (int)(gid >> 15);
  const int g = nt * 16 + (lane & 15);
  const int k = ks * 32 + (lane >> 4) * 8;
  const size_t so = ((size_t)n * kG + g) * kH + k;

  const float4 a0 = *(const float4*)(wa + so), a1 = *(const float4*)(wa + so + 4);
  const float4 b0 = *(const float4*)(wb + so), b1 = *(const float4*)(wb + so + 4);
  const float4 c0 = *(const float4*)(wc + so), c1 = *(const float4*)(wc + so + 4);
  bf16x8 va, vb, vc;
  va[0]=(bf16)a0.x; va[1]=(bf16)a0.y; va[2]=(bf16)a0.z; va[3]=(bf16)a0.w;
  va[4]=(bf16)a1.x; va[5]=(bf16)a1.y; va[6]=(bf16)a1.z; va[7]=(bf16)a1.w;
  vb[0]=(bf16)b0.x; vb[1]=(bf16)b0.y; vb[2]=(bf16)b0.z; vb[3]=(bf16)b0.w;
  vb[4]=(bf16)b1.x; vb[5]=(bf16)b1.y; vb[6]=(bf16)b1.z; vb[7]=(bf16)b1.w;
  vc[0]=(bf16)c0.x; vc[1]=(bf16)c0.y; vc[2]=(bf16)c0.z; vc[3]=(bf16)c0.w;
  vc[4]=(bf16)c1.x; vc[5]=(bf16)c1.y; vc[6]=(bf16)c1.z; vc[7]=(bf16)c1.w;
  ((bf16x8*)oa)[gid] = va;
  ((bf16x8*)ob)[gid] = vb;
  ((bf16x8*)oc)[gid] = vc;
}

// ---- two concurrent recurrent chains ----
// Payload layout per h-matrix: u64[c=0..255][mc=0..7], u64 = bf16 rows (mc*4..mc*4+3)
// of column c. Publisher-register-natural (rows vary with acc reg index r).
// Flag lines: 16 u32 (64 B) per (stream, slot); entry = producerWG*4 + wave.
__global__ __launch_bounds__(256) __attribute__((amdgpu_waves_per_eu(1, 1)))
void k_lstm(
    const float* __restrict__ x, const float* __restrict__ Wih1,
    const float* __restrict__ bih1, const float* __restrict__ bhh1,
    const float* __restrict__ bih2, const float* __restrict__ bhh2,
    const bf16* __restrict__ pk1, const bf16* __restrict__ pk2i,
    const bf16* __restrict__ pk2h, float* __restrict__ h2_final,
    u64* __restrict__ pay1, u64* __restrict__ pay2,
    u32* __restrict__ flags1, u32* __restrict__ flags2, u32* __restrict__ prog)
{
  const int blk = blockIdx.x;
  const int tid = threadIdx.x, wv = tid >> 6, lane = tid & 63;
  const int l15 = lane & 15, l4 = lane >> 4;

  __shared__ alignas(16) unsigned short hs1[kB][kHP];

  if (blk < 72) {
    // ================= L1: h1 chain; WG j owns h1-cols [j*128,(j+1)*128) =========
    const int n = blk >> 1, j = blk & 1;
    __shared__ float xsh[kT][kB];
    for (int i = tid; i < kB * kT; i += 256) {
      int b = i >> 7, t = i & 127;
      xsh[t][b] = x[((size_t)b * kT + t) * kN + n];
    }
    bf16x8 W[2][4][8]; // 256 VGPRs
    {
      const bf16x8* base = (const bf16x8*)pk1 + (size_t)n * 32768;
#pragma unroll
      for (int jj = 0; jj < 2; ++jj)
#pragma unroll
        for (int gt = 0; gt < 4; ++gt)
#pragma unroll
          for (int ks = 0; ks < 8; ++ks)
            W[jj][gt][ks] = base[(size_t)(gt * 16 + j * 8 + wv * 2 + jj) * 512 + ks * 64 + lane];
    }
    float wih[2][4], bg[2][4];
#pragma unroll
    for (int jj = 0; jj < 2; ++jj)
#pragma unroll
      for (int gt = 0; gt < 4; ++gt) {
        int g = gt * 256 + j * 128 + wv * 32 + jj * 16 + l15;
        wih[jj][gt] = Wih1[n * kG + g];
        bg[jj][gt] = bih1[n * kG + g] + bhh1[n * kG + g];
      }
    float cst[2][2][4];
#pragma unroll
    for (int a = 0; a < 2; ++a)
#pragma unroll
      for (int b = 0; b < 2; ++b)
#pragma unroll
        for (int r = 0; r < 4; ++r) cst[a][b][r] = 0.f;

    u64* payn = pay1 + (size_t)n * kD1 * 2048;
    u32* fl1 = flags1 + (size_t)n * kD1 * 16;
    u32* pg = prog + n * 4;
    const int pc0 = (1 - j) * 128, myb = j * 128 + wv * 32;
    __syncthreads();

#pragma unroll 1
    for (int t = 0; t < kT; ++t) {
      if ((t & 7) == 0 && t) { // ring back-pressure vs slowest L2 quarter
        if (tid == 0) {
          for (;;) {
            u32 m0 = pload32(&pg[0]), m1 = pload32(&pg[1]);
            u32 m2 = pload32(&pg[2]), m3 = pload32(&pg[3]);
            u32 mn = m0 < m1 ? m0 : m1;
            mn = mn < m2 ? mn : m2;
            mn = mn < m3 ? mn : m3;
            if ((int)mn + 8 >= t) break;
          }
        }
        __syncthreads();
      }
      f32x4 acc[2][2][4];
#pragma unroll
      for (int mt = 0; mt < 2; ++mt)
#pragma unroll
        for (int jj = 0; jj < 2; ++jj)
#pragma unroll
          for (int gt = 0; gt < 4; ++gt)
#pragma unroll
            for (int r = 0; r < 4; ++r)
              acc[mt][jj][gt][r] = xsh[t][mt * 16 + l4 * 4 + r] * wih[jj][gt] + bg[jj][gt];
      if (t > 0) {
        const int sl = (t - 1) % kD1;
        // sibling published h1(t-1) with flag value t (4 wave-flags)
        if (wv == 0 && lane < 4) wait_flag(fl1 + sl * 16 + (1 - j) * 4 + lane, (u32)t);
        __syncthreads();   // also protects hs1 own-half writes (t-1) vs reads (t)
        {
          const u64* ps = payn + (size_t)sl * 2048;
          const int c = pc0 + (tid >> 1), mb = (tid & 1) * 16;
          u64 v[4];
#pragma unroll
          for (int i = 0; i < 4; ++i)
            v[i] = pload(ps + (size_t)c * 8 + (tid & 1) * 4 + i);
#pragma unroll
          for (int i = 0; i < 4; ++i) {
            hs1[mb + 4 * i + 0][c] = (unsigned short)v[i];
            hs1[mb + 4 * i + 1][c] = (unsigned short)(v[i] >> 16);
            hs1[mb + 4 * i + 2][c] = (unsigned short)(v[i] >> 32);
            hs1[mb + 4 * i + 3][c] = (unsigned short)(v[i] >> 48);
          }
        }
        __syncthreads();
#pragma unroll
        for (int ks = 0; ks < 8; ++ks) {
          bf16x8 A0 = *(const bf16x8*)&hs1[l15][ks * 32 + l4 * 8];
          bf16x8 A1 = *(const bf16x8*)&hs1[16 + l15][ks * 32 + l4 * 8];
#pragma unroll
          for (int jj = 0; jj < 2; ++jj)
#pragma unroll
            for (int gt = 0; gt < 4; ++gt) {
              acc[0][jj][gt] = __builtin_amdgcn_mfma_f32_16x16x32_bf16(A0, W[jj][gt][ks], acc[0][jj][gt], 0, 0, 0);
              acc[1][jj][gt] = __builtin_amdgcn_mfma_f32_16x16x32_bf16(A1, W[jj][gt][ks], acc[1][jj][gt], 0, 0, 0);
            }
        }
      }
      float hv[2][2][4];
#pragma unroll
      for (int mt = 0; mt < 2; ++mt)
#pragma unroll
        for (int jj = 0; jj < 2; ++jj)
#pragma unroll
          for (int r = 0; r < 4; ++r) {
            float cc = sigm(acc[mt][jj][1][r]) * cst[mt][jj][r]
                     + sigm(acc[mt][jj][0][r]) * tanh_f(acc[mt][jj][2][r]);
            cst[mt][jj][r] = cc;
            hv[mt][jj][r] = sigm(acc[mt][jj][3][r]) * tanh_f(cc);
          }
      // publish h1(t): tagless bf16x4 payload
      u64* pub = payn + (size_t)(t % kD1) * 2048;
#pragma unroll
      for (int jj = 0; jj < 2; ++jj)
#pragma unroll
        for (int mt = 0; mt < 2; ++mt) {
          int c = myb + jj * 16 + l15;
          pstore(&pub[(size_t)c * 8 + mt * 4 + l4],
                 pack4(hv[mt][jj][0], hv[mt][jj][1], hv[mt][jj][2], hv[mt][jj][3]));
        }
      // local half straight into LDS for next step (overlaps store drain)
#pragma unroll
      for (int mt = 0; mt < 2; ++mt)
#pragma unroll
        for (int jj = 0; jj < 2; ++jj)
#pragma unroll
          for (int r = 0; r < 4; ++r)
            hs1[mt * 16 + l4 * 4 + r][myb + jj * 16 + l15] = f2bf(hv[mt][jj][r]);
      asm volatile("s_waitcnt vmcnt(0)" ::: "memory"); // payload at coherence point
      if (lane == 0) pstore32(fl1 + (t % kD1) * 16 + j * 4 + wv, (u32)(t + 1));
      // no loop-end barrier: next iteration's post-flag barrier protects hs1
    }
  } else {
    // ====== L2: h2 chain; WG q owns h2-cols [q*64,(q+1)*64); u in-register =======
    const int bb = blk - 72, n = bb >> 2, q = bb & 3;
    __shared__ alignas(16) unsigned short hs2[kB][kHP];

    bf16x8 Wi[4][8], Wh[4][8]; // 128 + 128 VGPRs
    {
      const bf16x8* bi = (const bf16x8*)pk2i + (size_t)n * 32768;
      const bf16x8* bh = (const bf16x8*)pk2h + (size_t)n * 32768;
#pragma unroll
      for (int gt = 0; gt < 4; ++gt)
#pragma unroll
        for (int ks = 0; ks < 8; ++ks) {
          size_t o = (size_t)(gt * 16 + q * 4 + wv) * 512 + ks * 64 + lane;
          Wi[gt][ks] = bi[o];
          Wh[gt][ks] = bh[o];
        }
    }
    const int col = q * 64 + wv * 16 + l15;
    float bg[4];
#pragma unroll
    for (int gt = 0; gt < 4; ++gt) {
      int g = gt * 256 + col;
      bg[gt] = bih2[n * kG + g] + bhh2[n * kG + g];
    }
    float cst[2][4];
#pragma unroll
    for (int mt = 0; mt < 2; ++mt)
#pragma unroll
      for (int r = 0; r < 4; ++r) cst[mt][r] = 0.f;

    u64* payn = pay1 + (size_t)n * kD1 * 2048;
    u64* p2n = pay2 + (size_t)n * 2 * 2048;
    u32* fl1 = flags1 + (size_t)n * kD1 * 16;
    u32* fl2 = flags2 + (size_t)n * 2 * 16;
    u32* pg = prog + n * 4 + q;
    __syncthreads();

#pragma unroll 1
    for (int t = 0; t < kT; ++t) {
      // (a) wait h1(t) [8 wave-flags] and h2(t-1) [16 wave-flags] concurrently
      if (wv == 0) {
        if (lane < 8) wait_flag(fl1 + (t % kD1) * 16 + lane, (u32)(t + 1));
        else if (t > 0 && lane < 24) wait_flag(fl2 + ((t - 1) & 1) * 16 + (lane - 8), (u32)t);
      }
      __syncthreads();
      // (b) bulk-load both payloads once, stage into hs1/hs2 (column c = tid)
      u64 v1[8], v2[8];
      const u64* ph1 = payn + (size_t)(t % kD1) * 2048;
#pragma unroll
      for (int i = 0; i < 8; ++i) v1[i] = pload(ph1 + (size_t)tid * 8 + i);
      if (t > 0) {
        const u64* ph2 = p2n + (size_t)((t - 1) & 1) * 2048;
#pragma unroll
        for (int i = 0; i < 8; ++i) v2[i] = pload(ph2 + (size_t)tid * 8 + i);
      }
#pragma unroll
      for (int i = 0; i < 8; ++i) {
        hs1[4 * i + 0][tid] = (unsigned short)v1[i];
        hs1[4 * i + 1][tid] = (unsigned short)(v1[i] >> 16);
        hs1[4 * i + 2][tid] = (unsigned short)(v1[i] >> 32);
        hs1[4 * i + 3][tid] = (unsigned short)(v1[i] >> 48);
      }
      if (t > 0) {
#pragma unroll
        for (int i = 0; i < 8; ++i) {
          hs2[4 * i + 0][tid] = (unsigned short)v2[i];
          hs2[4 * i + 1][tid] = (unsigned short)(v2[i] >> 16);
          hs2[4 * i + 2][tid] = (unsigned short)(v2[i] >> 32);
          hs2[4 * i + 3][tid] = (unsigned short)(v2[i] >> 48);
        }
      }
      __syncthreads();
      if (tid == 0) pstore32(pg, (u32)(t + 1)); // h1(t) staged; ring slot reusable
      // (c) u = Wih2 * h1(t) + bg2, then Whh2 * h2(t-1)
      f32x4 acc[2][4];
#pragma unroll
      for (int mt = 0; mt < 2; ++mt)
#pragma unroll
        for (int gt = 0; gt < 4; ++gt)
#pragma unroll
          for (int r = 0; r < 4; ++r) acc[mt][gt][r] = bg[gt];
#pragma unroll
      for (int ks = 0; ks < 8; ++ks) {
        bf16x8 A0 = *(const bf16x8*)&hs1[l15][ks * 32 + l4 * 8];
        bf16x8 A1 = *(const bf16x8*)&hs1[16 + l15][ks * 32 + l4 * 8];
#pragma unroll
        for (int gt = 0; gt < 4; ++gt) {
          acc[0][gt] = __builtin_amdgcn_mfma_f32_16x16x32_bf16(A0, Wi[gt][ks], acc[0][gt], 0, 0, 0);
          acc[1][gt] = __builtin_amdgcn_mfma_f32_16x16x32_bf16(A1, Wi[gt][ks], acc[1][gt], 0, 0, 0);
        }
      }
      if (t > 0) {
#pragma unroll
        for (int ks = 0; ks < 8; ++ks) {
          bf16x8 A0 = *(const bf16x8*)&hs2[l15][ks * 32 + l4 * 8];
          bf16x8 A1 = *(const bf16x8*)&hs2[16 + l15][ks * 32 + l4 * 8];
#pragma unroll
          for (int gt = 0; gt < 4; ++gt) {
            acc[0][gt] = __builtin_amdgcn_mfma_f32_16x16x32_bf16(A0, Wh[gt][ks], acc[0][gt], 0, 0, 0);
            acc[1][gt] = __builtin_amdgcn_mfma_f32_16x16x32_bf16(A1, Wh[gt][ks], acc[1][gt], 0, 0, 0);
          }
        }
      }
      // (d) cell + publish h2(t)
      float hv[2][4];
#pragma unroll
      for (int mt = 0; mt < 2; ++mt)
#pragma unroll
        for (int r = 0; r < 4; ++r) {
          float cc = sigm(acc[mt][1][r]) * cst[mt][r]
                   + sigm(acc[mt][0][r]) * tanh_f(acc[mt][2][r]);
          cst[mt][r] = cc;
          hv[mt][r] = sigm(acc[mt][3][r]) * tanh_f(cc);
        }
      u64* pub = p2n + (size_t)(t & 1) * 2048;
#pragma unroll
      for (int mt = 0; mt < 2; ++mt)
        pstore(&pub[(size_t)col * 8 + mt * 4 + l4],
               pack4(hv[mt][0], hv[mt][1], hv[mt][2], hv[mt][3]));
      if (t == kT - 1) {
#pragma unroll
        for (int mt = 0; mt < 2; ++mt)
#pragma unroll
          for (int r = 0; r < 4; ++r)
            h2_final[((size_t)n * kB + (mt * 16 + l4 * 4 + r)) * kH + col] = hv[mt][r];
      }
      asm volatile("s_waitcnt vmcnt(0)" ::: "memory"); // payload at coherence point
      if (lane == 0) pstore32(fl2 + (t & 1) * 16 + q * 4 + wv, (u32)(t + 1));
      // no loop-end barrier: next iteration's post-flag barrier protects hs1/hs2
    }
  }
}

// ---- head ----
__global__ __launch_bounds__(256) void k_head1(
    const float* __restrict__ spec, const float* __restrict__ Wspec,
    const float* __restrict__ bspec, const float* __restrict__ Wp1,
    const float* __restrict__ h2f, float* __restrict__ partial)
{
  const int kc = blockIdx.x;
  const int b = blockIdx.y;
  const int o = threadIdx.x;
  __shared__ float fs[kH];
  if (kc < kN) {
    fs[o] = h2f[((size_t)kc * kB + b) * kH + o];
  } else {
    float v = bspec[o];
#pragma unroll
    for (int s = 0; s < kSpec; ++s) v += spec[b * kSpec + s] * Wspec[s * kH + o];
    fs[o] = v;
  }
  __syncthreads();
  const float* __restrict__ wp = Wp1 + (size_t)kc * 256 * kH + o;
  float a = 0.f;
#pragma unroll 8
  for (int i = 0; i < 256; ++i) a += fs[i] * wp[(size_t)i * kH];
  partial[((size_t)kc * kB + b) * kH + o] = a;
}

__global__ __launch_bounds__(256) void k_head2(
    const float* __restrict__ bp1, const float* __restrict__ Wp2,
    const float* __restrict__ bp2, const float* __restrict__ partial,
    float* __restrict__ out)
{
  const int b = blockIdx.x;
  const int o = threadIdx.x;
  __shared__ float hid[kH];
  float a = bp1[o];
#pragma unroll
  for (int kc = 0; kc < kN + 1; ++kc) a += partial[((size_t)kc * kB + b) * kH + o];
  hid[o] = fmaxf(a, 0.f);
  __syncthreads();
  if (o < kOut) {
    float r = bp2[o];
#pragma unroll 8
    for (int h = 0; h < kH; ++h) r += hid[h] * Wp2[h * kOut + o];
    out[b * kOut + o] = r;
  }
}

extern "C" void kernel_launch(void* const* d_in, const int* in_sizes, int n_in,
                              void* d_out, int out_size, void* d_ws, size_t ws_size,
                              hipStream_t stream) {
  const float* x = (const float*)d_in[0];
  const float* spec = (const float*)d_in[1];
  const float* Wih1 = (const float*)d_in[2];
  const float* Whh1 = (const float*)d_in[3];
  const float* bih1 = (const float*)d_in[4];
  const float* bhh1 = (const float*)d_in[5];
  const float* Wih2 = (const float*)d_in[6];
  const float* Whh2 = (const float*)d_in[7];
  const float* bih2 = (const float*)d_in[8];
  const float* bhh2 = (const float*)d_in[9];
  const float* Wspec = (const float*)d_in[10];
  const float* bspec = (const float*)d_in[11];
  const float* Wp1 = (const float*)d_in[12];
  const float* bp1 = (const float*)d_in[13];
  const float* Wp2 = (const float*)d_in[14];
  const float* bp2 = (const float*)d_in[15];
  float* out = (float*)d_out;

  // ws (~70 MB): [prog 4K][flags1 36K][flags2 4.5K][pay1 9.4M][pay2 1.2M]
  //              [pk1|pk2i|pk2h 56.6M][h2_final 1.2M][partial 1.2M]
  // prog + all flags zeroed each launch (0 never matches wanted tags 1..128).
  const size_t WSZ = (size_t)kN * kG * kH;
  u32* prog = (u32*)d_ws;
  u32* flags1 = (u32*)((char*)d_ws + 4096);                 // 36*16*16 u32 = 36,864 B
  u32* flags2 = flags1 + (size_t)kN * kD1 * 16;             // 36*2*16 u32 = 4,608 B
  u64* pay1 = (u64*)((char*)d_ws + 45568);                  // 36*16*2048 u64 = 9.44 MB
  u64* pay2 = pay1 + (size_t)kN * kD1 * 2048;               // 36*2*2048 u64 = 1.18 MB
  bf16* pk1 = (bf16*)(pay2 + (size_t)kN * 2 * 2048);
  bf16* pk2i = pk1 + WSZ;
  bf16* pk2h = pk2i + WSZ;
  float* h2_final = (float*)(pk2h + WSZ);
  float* partial = h2_final + (size_t)kN * kB * kH;

  hipMemsetAsync(d_ws, 0, 45568, stream); // prog + flag lines

  const size_t groups = (size_t)kN * 64 * 8 * 64;
  k_convert<<<dim3((unsigned)((groups + 255) / 256)), dim3(256), 0, stream>>>(
      Whh1, Wih2, Whh2, pk1, pk2i, pk2h);
  k_lstm<<<dim3(216), dim3(256), 0, stream>>>(
      x, Wih1, bih1, bhh1, bih2, bhh2, pk1, pk2i, pk2h, h2_final,
      pay1, pay2, flags1, flags2, prog);
  k_head1<<<dim3(kN + 1, kB), dim3(256), 0, stream>>>(spec, Wspec, bspec, Wp1, h2_final, partial);
  k_head2<<<dim3(kB), dim3(256), 0, stream>>>(bp1, Wp2, bp2, partial, out);
}

// Round 3
// 875.118 us; speedup vs baseline: 1.3582x; 1.0238x over previous
//
#include <hip/hip_runtime.h>
#include <cstdint>
#include <cstddef>

// LSTMClassifier R9: self-validating tagged packets + hot spins + load/compute overlap.
// R8 post-mortem: sleep removal cut 25%; MfmaUtil*dur conserved -> duration tracks
// critical-path cycles 1:1. Remaining budget ~5900cy/step = ~8 serialized agent-RTTs
// across the two chains (drain -> flag -> detect -> bulk-load, twice).
// R9: packet = {tag:u32, 2 x bf16} u64, relaxed agent atomics, hot spin (no sleep).
//  - Producer: fire tagged stores; NO vmcnt drain, NO flag. Detection == data arrival.
//  - L1 sibling exchange: poll tagged half (8/thr), stage-on-detect. 1 exposed RTT.
//  - L2: h1(t+1) loads issued fire-and-forget right after h1(t) staged; validated at
//    loop end (hidden under Wih2-MFMA + h2-poll + Whh2-MFMA). h2 poll (16/thr) starts
//    after Wih2-MFMA, overlapping h2 packet propagation. ~1 exposed RTT per step.
// Stale-tag safety (no re-poison between graph replays): first wanted tag per slot
// never equals previous run's last tag (16-ring slot s: want s+1 vs stale 113+s;
// parity slots: want 1/2 vs stale 127/128); in-run reuse guarded by back-pressure
// window (8 < ring 16) and the quarters' <=1-step mutual lag. Only prog is memset.

constexpr int kN = 36, kH = 256, kG = 1024, kB = 32, kT = 128, kSpec = 6, kOut = 30;
constexpr int kHP = 264;   // LDS h stride (ushort)
constexpr int kD1 = 16;    // h1 ring depth (steps)

typedef __bf16 bf16;
typedef __bf16 bf16x8 __attribute__((ext_vector_type(8)));
typedef float f32x4 __attribute__((ext_vector_type(4)));
typedef unsigned long long u64;
typedef unsigned int u32;

__device__ __forceinline__ float sigm(float v) { return 1.f / (1.f + __expf(-v)); }
__device__ __forceinline__ float tanh_f(float v) {
  v = fminf(15.f, fmaxf(-15.f, v));
  float e = __expf(2.f * v);
  return (e - 1.f) / (e + 1.f);
}
__device__ __forceinline__ unsigned short f2bf(float f) {
  bf16 b = (bf16)f;
  return __builtin_bit_cast(unsigned short, b);
}
__device__ __forceinline__ u64 pload(const u64* p) {
  return __hip_atomic_load(p, __ATOMIC_RELAXED, __HIP_MEMORY_SCOPE_AGENT);
}
__device__ __forceinline__ void pstore(u64* p, u64 v) {
  __hip_atomic_store(p, v, __ATOMIC_RELAXED, __HIP_MEMORY_SCOPE_AGENT);
}
__device__ __forceinline__ u32 pload32(const u32* p) {
  return __hip_atomic_load(p, __ATOMIC_RELAXED, __HIP_MEMORY_SCOPE_AGENT);
}
__device__ __forceinline__ void pstore32(u32* p, u32 v) {
  __hip_atomic_store(p, v, __ATOMIC_RELAXED, __HIP_MEMORY_SCOPE_AGENT);
}

// Packet grid per h-matrix: p = m*256 + c, m=0..15 (rows m and m+16), c=0..255.
// payload: lo16 = row m, hi16 = row m+16, tag = high u32.

// issue 16 loads (p = i*256 + tid), fire-and-forget into v[]
__device__ __forceinline__ void issue16(const u64* __restrict__ base, int tid, u64* v) {
#pragma unroll
  for (int i = 0; i < 16; ++i) v[i] = pload(base + (size_t)i * 256 + tid);
}
// validate all 16 tags == want, re-loading misses (hot spin)
__device__ __forceinline__ void finish16(const u64* __restrict__ base, u32 want,
                                         int tid, u64* v) {
  u32 got = 0;
  for (;;) {
#pragma unroll
    for (int i = 0; i < 16; ++i)
      if (!(got & (1u << i)) && (u32)(v[i] >> 32) == want) got |= 1u << i;
    if (got == 0xFFFFu) return;
#pragma unroll
    for (int i = 0; i < 16; ++i)
      if (!(got & (1u << i))) v[i] = pload(base + (size_t)i * 256 + tid);
  }
}
// poll 16/thread, stage into hs on detect (col = tid)
__device__ __forceinline__ void poll16_stage(const u64* __restrict__ base, u32 want,
                                             int tid, unsigned short (*hs)[kHP]) {
  u64 v[16];
  u32 got = 0;
#pragma unroll
  for (int i = 0; i < 16; ++i) v[i] = pload(base + (size_t)i * 256 + tid);
  for (;;) {
#pragma unroll
    for (int i = 0; i < 16; ++i) {
      if (!(got & (1u << i)) && (u32)(v[i] >> 32) == want) {
        got |= 1u << i;
        hs[i][tid] = (unsigned short)v[i];
        hs[i + 16][tid] = (unsigned short)(v[i] >> 16);
      }
    }
    if (got == 0xFFFFu) return;
#pragma unroll
    for (int i = 0; i < 16; ++i)
      if (!(got & (1u << i))) v[i] = pload(base + (size_t)i * 256 + tid);
  }
}
// poll 8/thread over a 128-col half (cols [pc0,pc0+128)), stage on detect
__device__ __forceinline__ void poll8_stage(const u64* __restrict__ base, u32 want,
                                            int tid, int pc0, unsigned short (*hs)[kHP]) {
  const int c = pc0 + (tid & 127), m0 = (tid >> 7) * 8;
  u64 v[8];
  u32 got = 0;
#pragma unroll
  for (int i = 0; i < 8; ++i) v[i] = pload(base + (size_t)(m0 + i) * 256 + c);
  for (;;) {
#pragma unroll
    for (int i = 0; i < 8; ++i) {
      if (!(got & (1u << i)) && (u32)(v[i] >> 32) == want) {
        got |= 1u << i;
        hs[m0 + i][c] = (unsigned short)v[i];
        hs[m0 + i + 16][c] = (unsigned short)(v[i] >> 16);
      }
    }
    if (got == 0xFFu) return;
#pragma unroll
    for (int i = 0; i < 8; ++i)
      if (!(got & (1u << i))) v[i] = pload(base + (size_t)(m0 + i) * 256 + c);
  }
}

// ---- convert + permute weights fp32 -> bf16 MFMA B-fragment order ----
__global__ __launch_bounds__(256) void k_convert(
    const float* __restrict__ wa, const float* __restrict__ wb, const float* __restrict__ wc,
    bf16* __restrict__ oa, bf16* __restrict__ ob, bf16* __restrict__ oc)
{
  const size_t total = (size_t)kN * 64 * 8 * 64;
  size_t gid = (size_t)blockIdx.x * 256 + threadIdx.x;
  if (gid >= total) return;
  const int lane = (int)(gid & 63);
  const int ks = (int)((gid >> 6) & 7);
  const int nt = (int)((gid >> 9) & 63);
  const int n = (int)(gid >> 15);
  const int g = nt * 16 + (lane & 15);
  const int k = ks * 32 + (lane >> 4) * 8;
  const size_t so = ((size_t)n * kG + g) * kH + k;

  const float4 a0 = *(const float4*)(wa + so), a1 = *(const float4*)(wa + so + 4);
  const float4 b0 = *(const float4*)(wb + so), b1 = *(const float4*)(wb + so + 4);
  const float4 c0 = *(const float4*)(wc + so), c1 = *(const float4*)(wc + so + 4);
  bf16x8 va, vb, vc;
  va[0]=(bf16)a0.x; va[1]=(bf16)a0.y; va[2]=(bf16)a0.z; va[3]=(bf16)a0.w;
  va[4]=(bf16)a1.x; va[5]=(bf16)a1.y; va[6]=(bf16)a1.z; va[7]=(bf16)a1.w;
  vb[0]=(bf16)b0.x; vb[1]=(bf16)b0.y; vb[2]=(bf16)b0.z; vb[3]=(bf16)b0.w;
  vb[4]=(bf16)b1.x; vb[5]=(bf16)b1.y; vb[6]=(bf16)b1.z; vb[7]=(bf16)b1.w;
  vc[0]=(bf16)c0.x; vc[1]=(bf16)c0.y; vc[2]=(bf16)c0.z; vc[3]=(bf16)c0.w;
  vc[4]=(bf16)c1.x; vc[5]=(bf16)c1.y; vc[6]=(bf16)c1.z; vc[7]=(bf16)c1.w;
  ((bf16x8*)oa)[gid] = va;
  ((bf16x8*)ob)[gid] = vb;
  ((bf16x8*)oc)[gid] = vc;
}

// ---- two concurrent recurrent chains ----
__global__ __launch_bounds__(256) __attribute__((amdgpu_waves_per_eu(1, 1)))
void k_lstm(
    const float* __restrict__ x, const float* __restrict__ Wih1,
    const float* __restrict__ bih1, const float* __restrict__ bhh1,
    const float* __restrict__ bih2, const float* __restrict__ bhh2,
    const bf16* __restrict__ pk1, const bf16* __restrict__ pk2i,
    const bf16* __restrict__ pk2h, float* __restrict__ h2_final,
    u64* __restrict__ h1r, u64* __restrict__ h2r, u32* __restrict__ prog)
{
  const int blk = blockIdx.x;
  const int tid = threadIdx.x, wv = tid >> 6, lane = tid & 63;
  const int l15 = lane & 15, l4 = lane >> 4;

  __shared__ alignas(16) unsigned short hs1[kB][kHP];

  if (blk < 72) {
    // ================= L1: h1 chain; WG j owns h1-cols [j*128,(j+1)*128) =========
    const int n = blk >> 1, j = blk & 1;
    __shared__ float xsh[kT][kB];
    for (int i = tid; i < kB * kT; i += 256) {
      int b = i >> 7, t = i & 127;
      xsh[t][b] = x[((size_t)b * kT + t) * kN + n];
    }
    bf16x8 W[2][4][8]; // 256 VGPRs
    {
      const bf16x8* base = (const bf16x8*)pk1 + (size_t)n * 32768;
#pragma unroll
      for (int jj = 0; jj < 2; ++jj)
#pragma unroll
        for (int gt = 0; gt < 4; ++gt)
#pragma unroll
          for (int ks = 0; ks < 8; ++ks)
            W[jj][gt][ks] = base[(size_t)(gt * 16 + j * 8 + wv * 2 + jj) * 512 + ks * 64 + lane];
    }
    float wih[2][4], bg[2][4];
#pragma unroll
    for (int jj = 0; jj < 2; ++jj)
#pragma unroll
      for (int gt = 0; gt < 4; ++gt) {
        int g = gt * 256 + j * 128 + wv * 32 + jj * 16 + l15;
        wih[jj][gt] = Wih1[n * kG + g];
        bg[jj][gt] = bih1[n * kG + g] + bhh1[n * kG + g];
      }
    float cst[2][2][4];
#pragma unroll
    for (int a = 0; a < 2; ++a)
#pragma unroll
      for (int b = 0; b < 2; ++b)
#pragma unroll
        for (int r = 0; r < 4; ++r) cst[a][b][r] = 0.f;

    u64* ringn = h1r + (size_t)n * kD1 * 4096;
    u32* pg = prog + n * 4;
    const int pc0 = (1 - j) * 128, myb = j * 128 + wv * 32;
    __syncthreads();

#pragma unroll 1
    for (int t = 0; t < kT; ++t) {
      if ((t & 7) == 0 && t) { // ring back-pressure vs slowest L2 quarter
        if (tid == 0) {
          for (;;) {
            u32 m0 = pload32(&pg[0]), m1 = pload32(&pg[1]);
            u32 m2 = pload32(&pg[2]), m3 = pload32(&pg[3]);
            u32 mn = m0 < m1 ? m0 : m1;
            mn = mn < m2 ? mn : m2;
            mn = mn < m3 ? mn : m3;
            if ((int)mn + 8 >= t) break;
          }
        }
        __syncthreads();
      }
      f32x4 acc[2][2][4];
#pragma unroll
      for (int mt = 0; mt < 2; ++mt)
#pragma unroll
        for (int jj = 0; jj < 2; ++jj)
#pragma unroll
          for (int gt = 0; gt < 4; ++gt)
#pragma unroll
            for (int r = 0; r < 4; ++r)
              acc[mt][jj][gt][r] = xsh[t][mt * 16 + l4 * 4 + r] * wih[jj][gt] + bg[jj][gt];
      if (t > 0) {
        // sibling's half of h1(t-1): tagged poll, stage-on-detect. 1 exposed RTT.
        poll8_stage(ringn + (size_t)((t - 1) % kD1) * 4096, (u32)t, tid, pc0, hs1);
        __syncthreads();   // sibling staged + own-half writes (t-1) visible
#pragma unroll
        for (int ks = 0; ks < 8; ++ks) {
          bf16x8 A0 = *(const bf16x8*)&hs1[l15][ks * 32 + l4 * 8];
          bf16x8 A1 = *(const bf16x8*)&hs1[16 + l15][ks * 32 + l4 * 8];
#pragma unroll
          for (int jj = 0; jj < 2; ++jj)
#pragma unroll
            for (int gt = 0; gt < 4; ++gt) {
              acc[0][jj][gt] = __builtin_amdgcn_mfma_f32_16x16x32_bf16(A0, W[jj][gt][ks], acc[0][jj][gt], 0, 0, 0);
              acc[1][jj][gt] = __builtin_amdgcn_mfma_f32_16x16x32_bf16(A1, W[jj][gt][ks], acc[1][jj][gt], 0, 0, 0);
            }
        }
      }
      float hv[2][2][4];
#pragma unroll
      for (int mt = 0; mt < 2; ++mt)
#pragma unroll
        for (int jj = 0; jj < 2; ++jj)
#pragma unroll
          for (int r = 0; r < 4; ++r) {
            float cc = sigm(acc[mt][jj][1][r]) * cst[mt][jj][r]
                     + sigm(acc[mt][jj][0][r]) * tanh_f(acc[mt][jj][2][r]);
            cst[mt][jj][r] = cc;
            hv[mt][jj][r] = sigm(acc[mt][jj][3][r]) * tanh_f(cc);
          }
      // publish h1(t): tagged packets, own half (8/thread). No drain, no flag.
      u64* pub = ringn + (size_t)(t % kD1) * 4096;
      const u64 tagw = ((u64)(u32)(t + 1)) << 32;
#pragma unroll
      for (int jj = 0; jj < 2; ++jj)
#pragma unroll
        for (int r = 0; r < 4; ++r) {
          int c = myb + jj * 16 + l15, m = l4 * 4 + r;
          pstore(&pub[(size_t)m * 256 + c],
                 tagw | ((u64)f2bf(hv[1][jj][r]) << 16) | f2bf(hv[0][jj][r]));
        }
      // own half straight into LDS for next step
#pragma unroll
      for (int mt = 0; mt < 2; ++mt)
#pragma unroll
        for (int jj = 0; jj < 2; ++jj)
#pragma unroll
          for (int r = 0; r < 4; ++r)
            hs1[mt * 16 + l4 * 4 + r][myb + jj * 16 + l15] = f2bf(hv[mt][jj][r]);
      // no loop-end barrier: wave-skew argument (stage at t+1 happens >=850cy after
      // common barrier; MFMA(t) reads complete within ~620cy of it). R8-proven.
    }
  } else {
    // ====== L2: h2 chain; WG q owns h2-cols [q*64,(q+1)*64); u in-register =======
    const int bb = blk - 72, n = bb >> 2, q = bb & 3;
    __shared__ alignas(16) unsigned short hs2[kB][kHP];

    bf16x8 Wi[4][8], Wh[4][8]; // 128 + 128 VGPRs
    {
      const bf16x8* bi = (const bf16x8*)pk2i + (size_t)n * 32768;
      const bf16x8* bh = (const bf16x8*)pk2h + (size_t)n * 32768;
#pragma unroll
      for (int gt = 0; gt < 4; ++gt)
#pragma unroll
        for (int ks = 0; ks < 8; ++ks) {
          size_t o = (size_t)(gt * 16 + q * 4 + wv) * 512 + ks * 64 + lane;
          Wi[gt][ks] = bi[o];
          Wh[gt][ks] = bh[o];
        }
    }
    const int col = q * 64 + wv * 16 + l15;
    float bg[4];
#pragma unroll
    for (int gt = 0; gt < 4; ++gt) {
      int g = gt * 256 + col;
      bg[gt] = bih2[n * kG + g] + bhh2[n * kG + g];
    }
    float cst[2][4];
#pragma unroll
    for (int mt = 0; mt < 2; ++mt)
#pragma unroll
      for (int r = 0; r < 4; ++r) cst[mt][r] = 0.f;

    u64* ringn = h1r + (size_t)n * kD1 * 4096;
    u64* h2n = h2r + (size_t)n * 2 * 4096;
    u32* pg = prog + n * 4 + q;
    __syncthreads();

    // prologue: h1(0), ring slot 0, tag 1
    u64 v1[16];
    issue16(ringn, tid, v1);
    finish16(ringn, 1u, tid, v1);

#pragma unroll 1
    for (int t = 0; t < kT; ++t) {
      // (A) stage prefetched h1(t) into hs1
#pragma unroll
      for (int i = 0; i < 16; ++i) {
        hs1[i][tid] = (unsigned short)v1[i];
        hs1[i + 16][tid] = (unsigned short)(v1[i] >> 16);
      }
      __syncthreads();
      if (tid == 0) pstore32(pg, (u32)(t + 1)); // h1(t) consumed; ring slot reusable
      // (B) fire h1(t+1) prefetch loads; validated at loop end
      const u64* pn = ringn + (size_t)((t + 1) % kD1) * 4096;
      if (t + 1 < kT) issue16(pn, tid, v1);
      // (C) u = Wih2 * h1(t) + bg2 (overlaps h2 packet propagation)
      f32x4 acc[2][4];
#pragma unroll
      for (int mt = 0; mt < 2; ++mt)
#pragma unroll
        for (int gt = 0; gt < 4; ++gt)
#pragma unroll
          for (int r = 0; r < 4; ++r) acc[mt][gt][r] = bg[gt];
#pragma unroll
      for (int ks = 0; ks < 8; ++ks) {
        bf16x8 A0 = *(const bf16x8*)&hs1[l15][ks * 32 + l4 * 8];
        bf16x8 A1 = *(const bf16x8*)&hs1[16 + l15][ks * 32 + l4 * 8];
#pragma unroll
        for (int gt = 0; gt < 4; ++gt) {
          acc[0][gt] = __builtin_amdgcn_mfma_f32_16x16x32_bf16(A0, Wi[gt][ks], acc[0][gt], 0, 0, 0);
          acc[1][gt] = __builtin_amdgcn_mfma_f32_16x16x32_bf16(A1, Wi[gt][ks], acc[1][gt], 0, 0, 0);
        }
      }
      // (D) h2(t-1): tagged poll + stage, then Whh2 MFMA
      if (t > 0) {
        poll16_stage(h2n + (size_t)((t - 1) & 1) * 4096, (u32)t, tid, hs2);
        __syncthreads();
#pragma unroll
        for (int ks = 0; ks < 8; ++ks) {
          bf16x8 A0 = *(const bf16x8*)&hs2[l15][ks * 32 + l4 * 8];
          bf16x8 A1 = *(const bf16x8*)&hs2[16 + l15][ks * 32 + l4 * 8];
#pragma unroll
          for (int gt = 0; gt < 4; ++gt) {
            acc[0][gt] = __builtin_amdgcn_mfma_f32_16x16x32_bf16(A0, Wh[gt][ks], acc[0][gt], 0, 0, 0);
            acc[1][gt] = __builtin_amdgcn_mfma_f32_16x16x32_bf16(A1, Wh[gt][ks], acc[1][gt], 0, 0, 0);
          }
        }
      }
      // (E) cell + publish h2(t) tagged (4/thread). No drain, no flag.
      float hv[2][4];
#pragma unroll
      for (int mt = 0; mt < 2; ++mt)
#pragma unroll
        for (int r = 0; r < 4; ++r) {
          float cc = sigm(acc[mt][1][r]) * cst[mt][r]
                   + sigm(acc[mt][0][r]) * tanh_f(acc[mt][2][r]);
          cst[mt][r] = cc;
          hv[mt][r] = sigm(acc[mt][3][r]) * tanh_f(cc);
        }
      u64* pub = h2n + (size_t)(t & 1) * 4096;
      const u64 tagw = ((u64)(u32)(t + 1)) << 32;
#pragma unroll
      for (int r = 0; r < 4; ++r) {
        int m = l4 * 4 + r;
        pstore(&pub[(size_t)m * 256 + col],
               tagw | ((u64)f2bf(hv[1][r]) << 16) | f2bf(hv[0][r]));
      }
      if (t == kT - 1) {
#pragma unroll
        for (int mt = 0; mt < 2; ++mt)
#pragma unroll
          for (int r = 0; r < 4; ++r)
            h2_final[((size_t)n * kB + (mt * 16 + l4 * 4 + r)) * kH + col] = hv[mt][r];
      }
      // (F) validate h1(t+1) prefetch (usually already arrived)
      if (t + 1 < kT) finish16(pn, (u32)(t + 2), tid, v1);
      __syncthreads(); // all MFMA reads done before staging at next (A)
    }
  }
}

// ---- head ----
__global__ __launch_bounds__(256) void k_head1(
    const float* __restrict__ spec, const float* __restrict__ Wspec,
    const float* __restrict__ bspec, const float* __restrict__ Wp1,
    const float* __restrict__ h2f, float* __restrict__ partial)
{
  const int kc = blockIdx.x;
  const int b = blockIdx.y;
  const int o = threadIdx.x;
  __shared__ float fs[kH];
  if (kc < kN) {
    fs[o] = h2f[((size_t)kc * kB + b) * kH + o];
  } else {
    float v = bspec[o];
#pragma unroll
    for (int s = 0; s < kSpec; ++s) v += spec[b * kSpec + s] * Wspec[s * kH + o];
    fs[o] = v;
  }
  __syncthreads();
  const float* __restrict__ wp = Wp1 + (size_t)kc * 256 * kH + o;
  float a = 0.f;
#pragma unroll 8
  for (int i = 0; i < 256; ++i) a += fs[i] * wp[(size_t)i * kH];
  partial[((size_t)kc * kB + b) * kH + o] = a;
}

__global__ __launch_bounds__(256) void k_head2(
    const float* __restrict__ bp1, const float* __restrict__ Wp2,
    const float* __restrict__ bp2, const float* __restrict__ partial,
    float* __restrict__ out)
{
  const int b = blockIdx.x;
  const int o = threadIdx.x;
  __shared__ float hid[kH];
  float a = bp1[o];
#pragma unroll
  for (int kc = 0; kc < kN + 1; ++kc) a += partial[((size_t)kc * kB + b) * kH + o];
  hid[o] = fmaxf(a, 0.f);
  __syncthreads();
  if (o < kOut) {
    float r = bp2[o];
#pragma unroll 8
    for (int h = 0; h < kH; ++h) r += hid[h] * Wp2[h * kOut + o];
    out[b * kOut + o] = r;
  }
}

extern "C" void kernel_launch(void* const* d_in, const int* in_sizes, int n_in,
                              void* d_out, int out_size, void* d_ws, size_t ws_size,
                              hipStream_t stream) {
  const float* x = (const float*)d_in[0];
  const float* spec = (const float*)d_in[1];
  const float* Wih1 = (const float*)d_in[2];
  const float* Whh1 = (const float*)d_in[3];
  const float* bih1 = (const float*)d_in[4];
  const float* bhh1 = (const float*)d_in[5];
  const float* Wih2 = (const float*)d_in[6];
  const float* Whh2 = (const float*)d_in[7];
  const float* bih2 = (const float*)d_in[8];
  const float* bhh2 = (const float*)d_in[9];
  const float* Wspec = (const float*)d_in[10];
  const float* bspec = (const float*)d_in[11];
  const float* Wp1 = (const float*)d_in[12];
  const float* bp1 = (const float*)d_in[13];
  const float* Wp2 = (const float*)d_in[14];
  const float* bp2 = (const float*)d_in[15];
  float* out = (float*)d_out;

  // ws (~80 MB): [prog 4K][h1r 18.9M][h2r 2.4M][pk1|pk2i|pk2h 56.6M][h2_final][partial]
  // Only prog is memset; tagged rings are self-validating (stale tags never match).
  const size_t WSZ = (size_t)kN * kG * kH;
  u32* prog = (u32*)d_ws;
  u64* h1r = (u64*)((char*)d_ws + 4096);                    // 36*16*4096 u64 = 18.87 MB
  u64* h2r = h1r + (size_t)kN * kD1 * 4096;                 // 36*2*4096 u64 = 2.36 MB
  bf16* pk1 = (bf16*)(h2r + (size_t)kN * 2 * 4096);
  bf16* pk2i = pk1 + WSZ;
  bf16* pk2h = pk2i + WSZ;
  float* h2_final = (float*)(pk2h + WSZ);
  float* partial = h2_final + (size_t)kN * kB * kH;

  hipMemsetAsync(d_ws, 0, 4096, stream); // progress counters only

  const size_t groups = (size_t)kN * 64 * 8 * 64;
  k_convert<<<dim3((unsigned)((groups + 255) / 256)), dim3(256), 0, stream>>>(
      Whh1, Wih2, Whh2, pk1, pk2i, pk2h);
  k_lstm<<<dim3(216), dim3(256), 0, stream>>>(
      x, Wih1, bih1, bhh1, bih2, bhh2, pk1, pk2i, pk2h, h2_final, h1r, h2r, prog);
  k_head1<<<dim3(kN + 1, kB), dim3(256), 0, stream>>>(spec, Wspec, bspec, Wp1, h2_final, partial);
  k_head2<<<dim3(kB), dim3(256), 0, stream>>>(bp1, Wp2, bp2, partial, out);
}